// Round 11
// baseline (881.224 us; speedup 1.0000x reference)
//
#include <hip/hip_runtime.h>
#include <hip/hip_bf16.h>
#include <float.h>

#define DIN   768
#define DSAE  16384
#define K_    32
#define KTOT  2304
#define TD    12288   // 16*768
#define KSPLIT 8
#define KLEN   288    // KTOT/KSPLIT
#define KC     32     // 128B-aligned k-chunks
#define NCH    9      // KLEN/KC
#define SB     256    // s-rows per enc block
#define WSTR   36
#define NREP   12     // PROBE: amplify enc so it tops the rocprof table

#define FMA4(ACC, S, A) { ACC.x += (S) * (A).x; ACC.y += (S) * (A).y; \
                          ACC.z += (S) * (A).z; ACC.w += (S) * (A).w; }

// ---------------- Kernel 1: prep — build A_T[k][b], k = d*3+j ----------------
__global__ __launch_bounds__(256) void prep_kernel(const float* __restrict__ x,
                                                   float* __restrict__ A_T) {
    int g = blockIdx.x * 256 + threadIdx.x;      // 0..24575
    int b = g / DIN;
    int d = g - b * DIN;
    const float* xp = x + (size_t)b * TD + d;
    float S = 0.f;
    float x0 = xp[0];
    float xl = xp[15 * DIN];
    #pragma unroll
    for (int t = 0; t < 16; ++t) S += xp[t * DIN];
    int base = d * 96 + b;                       // (d*3+j)*32 + b
    A_T[base]      = S - xl;                     // j=0
    A_T[base + 32] = S;                          // j=1
    A_T[base + 64] = S - x0;                     // j=2
}

// ------------- Kernel 2: encode GEMM probe (XCD-swizzled, x12 reps) -------------
// Swizzle: all 8 k-split blocks of one s-tile land on ONE XCD (bid&7 const)
// so the 8x1152B slices of each W row issue together -> DRAM page hits.
__global__ __launch_bounds__(256, 2) void enc_gemm_kernel(
    const float* __restrict__ W,      // conv_w (16384 x 2304)
    const float* __restrict__ A_T,    // (2304 x 32)
    float* __restrict__ partial)      // (8 x 32 x 16384)
{
    __shared__ float Wt[SB * WSTR];   // 36864 B

    const int tid  = threadIdx.x;
    const int bid  = blockIdx.x;
    // XCD-aware remap: (s_tile, ks) <- bid such that bid&7 fixed per s_tile
    const int ks    = (bid >> 6) & 7;
    const int stile = ((bid & 7) << 3) | ((bid >> 3) & 7);
    const int s0    = stile * SB;
    const int koff  = ks * KLEN;
    const int l    = tid & 63;
    const int w    = tid >> 6;

    const float* Au = A_T + koff * 32 + __builtin_amdgcn_readfirstlane(w << 3);

    #pragma unroll 1
    for (int rep = 0; rep < NREP; ++rep) {
        // W chunk-0 prefetch (8 float4/thread, 128B-aligned rows)
        float4 wreg[8];
        #pragma unroll
        for (int i = 0; i < 8; ++i) {
            int f4 = tid + (i << 8);             // 0..2047
            int row = f4 >> 3, c = (f4 & 7) << 2;
            wreg[i] = *(const float4*)&W[(size_t)(s0 + row) * KTOT + koff + c];
        }

        float4 acc0[4], acc1[4];
        #pragma unroll
        for (int m = 0; m < 4; ++m) {
            acc0[m] = make_float4(0.f, 0.f, 0.f, 0.f);
            acc1[m] = make_float4(0.f, 0.f, 0.f, 0.f);
        }

        #pragma unroll 1
        for (int ch = 0; ch < NCH; ++ch) {
            __syncthreads();                     // prev compute/reads done
            #pragma unroll
            for (int i = 0; i < 8; ++i) {
                int f4 = tid + (i << 8);
                int row = f4 >> 3, c = (f4 & 7) << 2;
                *(float4*)&Wt[row * WSTR + c] = wreg[i];
            }
            __syncthreads();

            if (ch + 1 < NCH) {                  // prefetch next W chunk under compute
                const int kc = (ch + 1) * KC;
                #pragma unroll
                for (int i = 0; i < 8; ++i) {
                    int f4 = tid + (i << 8);
                    int row = f4 >> 3, c = (f4 & 7) << 2;
                    wreg[i] = *(const float4*)&W[(size_t)(s0 + row) * KTOT + koff + kc + c];
                }
            }

            #pragma unroll
            for (int g = 0; g < 8; ++g) {
                const int kk0 = g << 2;
                float4 a0[4], a1[4];
                #pragma unroll
                for (int d = 0; d < 4; ++d) {
                    const int k = ch * KC + kk0 + d;
                    a0[d] = *(const float4*)&Au[k * 32];       // s_load (wave-uniform)
                    a1[d] = *(const float4*)&Au[k * 32 + 4];
                }
                #pragma unroll
                for (int m = 0; m < 4; ++m) {
                    float4 wv = *(const float4*)&Wt[(l + (m << 6)) * WSTR + kk0];
                    FMA4(acc0[m], wv.x, a0[0]); FMA4(acc0[m], wv.y, a0[1]);
                    FMA4(acc0[m], wv.z, a0[2]); FMA4(acc0[m], wv.w, a0[3]);
                    FMA4(acc1[m], wv.x, a1[0]); FMA4(acc1[m], wv.y, a1[1]);
                    FMA4(acc1[m], wv.z, a1[2]); FMA4(acc1[m], wv.w, a1[3]);
                }
            }
        }

        // partial[ks][b][s], coalesced over l (idempotent across reps)
        float* pb = partial + (size_t)(ks * 32 + (w << 3)) * DSAE + s0 + l;
        #pragma unroll
        for (int m = 0; m < 4; ++m) {
            const int so = m << 6;
            pb[(size_t)0 * DSAE + so] = acc0[m].x;
            pb[(size_t)1 * DSAE + so] = acc0[m].y;
            pb[(size_t)2 * DSAE + so] = acc0[m].z;
            pb[(size_t)3 * DSAE + so] = acc0[m].w;
            pb[(size_t)4 * DSAE + so] = acc1[m].x;
            pb[(size_t)5 * DSAE + so] = acc1[m].y;
            pb[(size_t)6 * DSAE + so] = acc1[m].z;
            pb[(size_t)7 * DSAE + so] = acc1[m].w;
        }
        __syncthreads();                         // stores/reads drained before next rep
    }
}

// ---------------- Kernel 3: combine K-split partials + bias (streaming) ----------------
__global__ __launch_bounds__(256) void combine_kernel(const float* __restrict__ partial,
                                                      const float* __restrict__ b_enc,
                                                      float* __restrict__ pre,
                                                      float* __restrict__ out0) {
    int g  = blockIdx.x * 256 + threadIdx.x;     // float4 index, 0..131071
    int b  = g >> 12;
    int s4 = g & 4095;
    const float4* p = (const float4*)partial;
    float4 acc = p[(size_t)b * 4096 + s4];
    #pragma unroll
    for (int ks = 1; ks < KSPLIT; ++ks) {
        float4 v = p[(size_t)(ks * 32 + b) * 4096 + s4];
        acc.x += v.x; acc.y += v.y; acc.z += v.z; acc.w += v.w;
    }
    float4 be = ((const float4*)b_enc)[s4];
    acc.x += be.x; acc.y += be.y; acc.z += be.z; acc.w += be.w;
    ((float4*)pre)[(size_t)b * 4096 + s4] = acc;
    if (g == 0) *out0 = 0.f;
}

// ---------------- Kernel 4: top-k via 4-pass radix select (exact lax.top_k) ----------------
__global__ __launch_bounds__(1024, 1) void topk_kernel(
    float* __restrict__ z,            // in: pre (32 x DSAE); out: sparse z
    float* __restrict__ sel_val,
    int*   __restrict__ sel_idx)
{
    __shared__ unsigned hist[256];
    __shared__ unsigned gsfx[65];
    __shared__ unsigned sfx[257];
    __shared__ int      sdelta;
    __shared__ unsigned scnt;
    __shared__ int      l_idx[K_];
    __shared__ float    l_val[K_];
    __shared__ int      eq_min;

    const int t = threadIdx.x;
    const int b = blockIdx.x;
    float* zrow = z + (size_t)b * DSAE;

    float v[16]; unsigned u[16];
    #pragma unroll
    for (int i = 0; i < 16; ++i) {
        float f = zrow[t + (i << 10)];
        v[i] = f;
        unsigned xb = __float_as_uint(f);
        u[i] = (xb & 0x80000000u) ? ~xb : (xb | 0x80000000u);
    }

    unsigned prefix = 0, pmask = 0;
    int need = K_;

    for (int p = 0; p < 4; ++p) {
        const int shift = 24 - 8 * p;
        if (t < 256) hist[t] = 0;
        __syncthreads();
        #pragma unroll
        for (int i = 0; i < 16; ++i)
            if ((u[i] & pmask) == prefix)
                atomicAdd(&hist[(u[i] >> shift) & 255u], 1u);
        __syncthreads();
        if (t < 64) {
            unsigned s4 = hist[4*t] + hist[4*t+1] + hist[4*t+2] + hist[4*t+3];
            #pragma unroll
            for (int off = 1; off < 64; off <<= 1) {
                unsigned o = __shfl_down(s4, off, 64);
                if (t + off < 64) s4 += o;
            }
            gsfx[t] = s4;
            if (t == 0) gsfx[64] = 0;
        }
        __syncthreads();
        if (t < 256) {
            int q = t >> 2;
            unsigned acc = gsfx[q + 1];
            for (int d = 4*q + 3; d >= t; --d) acc += hist[d];
            sfx[t] = acc;
            if (t == 0) sfx[256] = 0;
        }
        __syncthreads();
        if (t < 256) {
            if (sfx[t] >= (unsigned)need && sfx[t + 1] < (unsigned)need) sdelta = t;
        }
        __syncthreads();
        const int dlt = sdelta;
        need  -= (int)sfx[dlt + 1];
        prefix |= ((unsigned)dlt) << shift;
        pmask  |= 0xFFu << shift;
        __syncthreads();
    }

    const unsigned ustar = prefix;
    if (t == 0) scnt = 0;
    __syncthreads();

    unsigned eqmask = 0;
    #pragma unroll
    for (int i = 0; i < 16; ++i) {
        int idx = t + (i << 10);
        if (u[i] > ustar) {
            unsigned s = atomicAdd(&scnt, 1u);
            l_idx[s] = idx; l_val[s] = v[i];
        } else if (u[i] == ustar) {
            eqmask |= (1u << i);
        }
    }
    __syncthreads();
    const int needf = need;
    for (int r = 0; r < needf; ++r) {
        if (t == 0) eq_min = 0x7FFFFFFF;
        __syncthreads();
        #pragma unroll
        for (int i = 0; i < 16; ++i)
            if (eqmask & (1u << i)) atomicMin(&eq_min, t + (i << 10));
        __syncthreads();
        #pragma unroll
        for (int i = 0; i < 16; ++i)
            if ((eqmask & (1u << i)) && (t + (i << 10) == eq_min)) {
                eqmask &= ~(1u << i);
                unsigned s = atomicAdd(&scnt, 1u);
                l_idx[s] = eq_min; l_val[s] = v[i];
            }
        __syncthreads();
    }

    #pragma unroll
    for (int i = 0; i < 16; ++i) zrow[t + (i << 10)] = 0.f;
    __syncthreads();
    if (t == 0) {
        for (int a = 1; a < K_; ++a) {
            int ia = l_idx[a]; float va = l_val[a]; int c = a - 1;
            while (c >= 0 && l_idx[c] > ia) {
                l_idx[c+1] = l_idx[c]; l_val[c+1] = l_val[c]; --c;
            }
            l_idx[c+1] = ia; l_val[c+1] = va;
        }
    }
    __syncthreads();
    if (t < K_) {
        float val = l_val[t] > 0.f ? l_val[t] : 0.f;
        zrow[l_idx[t]] = val;
        sel_val[(b << 5) + t] = val;
        sel_idx[(b << 5) + t] = l_idx[t];
    }
}

// ---------------- Kernel 5: sparse decode + fused sq-err, atomic loss ----------------
__global__ __launch_bounds__(256, 4) void decode_kernel(
    const float* __restrict__ W_dec,
    const float* __restrict__ b_dec,
    const float* __restrict__ x,
    const float* __restrict__ sel_val,
    const int*   __restrict__ sel_idx,
    float* __restrict__ xhat,          // d_out + 1
    float* __restrict__ out0)
{
    __shared__ float sv[K_];
    __shared__ int   si[K_];
    __shared__ float wsum[4];

    const int t     = threadIdx.x;
    const int blk   = blockIdx.x;
    const int b     = blk / 12;
    const int chunk = blk - b * 12;

    if (t < K_) { sv[t] = sel_val[(b << 5) + t]; si[t] = sel_idx[(b << 5) + t]; }
    __syncthreads();

    const int e = chunk * 1024 + t * 4;
    float4 acc = *(const float4*)&b_dec[e];
    #pragma unroll 8
    for (int j = 0; j < K_; ++j) {
        const float val = sv[j];
        const float4 wd = *(const float4*)&W_dec[(size_t)si[j] * TD + e];
        acc.x += val * wd.x;
        acc.y += val * wd.y;
        acc.z += val * wd.z;
        acc.w += val * wd.w;
    }

    const size_t xo = (size_t)b * TD + e;
    xhat[xo + 0] = acc.x;
    xhat[xo + 1] = acc.y;
    xhat[xo + 2] = acc.z;
    xhat[xo + 3] = acc.w;

    const float4 xv = *(const float4*)&x[xo];
    float dx = acc.x - xv.x, dy = acc.y - xv.y;
    float dz = acc.z - xv.z, dw = acc.w - xv.w;
    float ss = dx * dx + dy * dy + dz * dz + dw * dw;
    #pragma unroll
    for (int off = 32; off > 0; off >>= 1) ss += __shfl_down(ss, off, 64);
    if ((t & 63) == 0) wsum[t >> 6] = ss;
    __syncthreads();
    if (t == 0)
        atomicAdd(out0, (wsum[0] + wsum[1] + wsum[2] + wsum[3]) * (1.0f / 512.0f));
}

extern "C" void kernel_launch(void* const* d_in, const int* in_sizes, int n_in,
                              void* d_out, int out_size, void* d_ws, size_t ws_size,
                              hipStream_t stream) {
    const float* x      = (const float*)d_in[0];
    const float* conv_w = (const float*)d_in[1];
    const float* b_enc  = (const float*)d_in[2];
    const float* W_dec  = (const float*)d_in[3];
    const float* b_dec  = (const float*)d_in[4];

    float* out  = (float*)d_out;
    float* xhat = out + 1;                        // (32,16,768)
    float* z    = out + 1 + 393216;               // (32,16384) — holds pre then sparse z

    float* partial_enc = (float*)d_ws;                          // 16.8 MB
    float* A_T         = (float*)((char*)d_ws + (20u << 20));   // 288 KB
    float* sel_val     = (float*)((char*)d_ws + (21u << 20));
    int*   sel_idx     = (int*)  ((char*)d_ws + (21u << 20) + 4096);

    prep_kernel    <<<96,  256,  0, stream>>>(x, A_T);
    enc_gemm_kernel<<<512, 256,  0, stream>>>(conv_w, A_T, partial_enc);
    combine_kernel <<<512, 256,  0, stream>>>(partial_enc, b_enc, z, out);
    topk_kernel    <<<32,  1024, 0, stream>>>(z, sel_val, sel_idx);
    decode_kernel  <<<384, 256,  0, stream>>>(W_dec, b_dec, x, sel_val, sel_idx, xhat, out);
}

// Round 12
// 139.031 us; speedup vs baseline: 6.3383x; 6.3383x over previous
//
#include <hip/hip_runtime.h>
#include <hip/hip_bf16.h>
#include <float.h>

#define DIN   768
#define DSAE  16384
#define K_    32
#define KTOT  2304
#define TD    12288   // 16*768
#define KSPLIT 8
#define KLEN   288    // KTOT/KSPLIT
#define KC     32     // 128B-aligned k-chunks
#define NCH    9      // KLEN/KC
#define SB     64     // s-rows per enc block -> grid 2048, high occupancy
#define WSTR   36

#define FMA4(ACC, S, A) { ACC.x += (S) * (A).x; ACC.y += (S) * (A).y; \
                          ACC.z += (S) * (A).z; ACC.w += (S) * (A).w; }

// ---------------- Kernel 1: prep — build A_T[k][b], k = d*3+j ----------------
__global__ __launch_bounds__(256) void prep_kernel(const float* __restrict__ x,
                                                   float* __restrict__ A_T) {
    int g = blockIdx.x * 256 + threadIdx.x;      // 0..24575
    int b = g / DIN;
    int d = g - b * DIN;
    const float* xp = x + (size_t)b * TD + d;
    float S = 0.f;
    float x0 = xp[0];
    float xl = xp[15 * DIN];
    #pragma unroll
    for (int t = 0; t < 16; ++t) S += xp[t * DIN];
    int base = d * 96 + b;                       // (d*3+j)*32 + b
    A_T[base]      = S - xl;                     // j=0
    A_T[base + 32] = S;                          // j=1
    A_T[base + 64] = S - x0;                     // j=2
}

// ------------- Kernel 2: encode GEMM (64s x 32b tile, occupancy fix) -------------
// grid = 256 s-tiles x 8 k-splits = 2048 blocks (up to 8/CU, 32 waves/CU).
// lane l owns s-row s0+l; wave w owns b = 8w..8w+7. A via wave-uniform s_load.
__global__ __launch_bounds__(256, 4) void enc_gemm_kernel(
    const float* __restrict__ W,      // conv_w (16384 x 2304)
    const float* __restrict__ A_T,    // (2304 x 32)
    float* __restrict__ partial)      // (8 x 32 x 16384)
{
    __shared__ float Wt[SB * WSTR];   // 9216 B

    const int tid  = threadIdx.x;
    const int bid  = blockIdx.x;
    const int ks   = bid & 7;
    const int s0   = (bid >> 3) * SB;
    const int koff = ks * KLEN;
    const int l    = tid & 63;
    const int w    = tid >> 6;

    const float* Au = A_T + koff * 32 + __builtin_amdgcn_readfirstlane(w << 3);

    // W chunk-0 prefetch (2 float4/thread, 128B-aligned rows)
    float4 wreg[2];
    #pragma unroll
    for (int i = 0; i < 2; ++i) {
        int f4  = tid + (i << 8);                // 0..511
        int row = f4 >> 3, c = (f4 & 7) << 2;
        wreg[i] = *(const float4*)&W[(size_t)(s0 + row) * KTOT + koff + c];
    }

    float4 acc0 = make_float4(0.f, 0.f, 0.f, 0.f);
    float4 acc1 = make_float4(0.f, 0.f, 0.f, 0.f);

    #pragma unroll 1
    for (int ch = 0; ch < NCH; ++ch) {
        __syncthreads();                         // prev compute done
        #pragma unroll
        for (int i = 0; i < 2; ++i) {
            int f4  = tid + (i << 8);
            int row = f4 >> 3, c = (f4 & 7) << 2;
            *(float4*)&Wt[row * WSTR + c] = wreg[i];
        }
        __syncthreads();

        if (ch + 1 < NCH) {                      // prefetch next W chunk under compute
            const int kc = (ch + 1) * KC;
            #pragma unroll
            for (int i = 0; i < 2; ++i) {
                int f4  = tid + (i << 8);
                int row = f4 >> 3, c = (f4 & 7) << 2;
                wreg[i] = *(const float4*)&W[(size_t)(s0 + row) * KTOT + koff + kc + c];
            }
        }

        #pragma unroll
        for (int g = 0; g < 8; ++g) {
            const int kk0 = g << 2;
            const float4 wv = *(const float4*)&Wt[l * WSTR + kk0];
            #pragma unroll
            for (int d = 0; d < 4; ++d) {
                const int k = ch * KC + kk0 + d;
                const float4 a0 = *(const float4*)&Au[k * 32];       // s_load
                const float4 a1 = *(const float4*)&Au[k * 32 + 4];   // s_load
                const float ww = (&wv.x)[d];
                FMA4(acc0, ww, a0);
                FMA4(acc1, ww, a1);
            }
        }
    }

    // partial[ks][b][s0+l], coalesced over l
    float* pb = partial + (size_t)(ks * 32 + (w << 3)) * DSAE + s0 + l;
    pb[(size_t)0 * DSAE] = acc0.x;
    pb[(size_t)1 * DSAE] = acc0.y;
    pb[(size_t)2 * DSAE] = acc0.z;
    pb[(size_t)3 * DSAE] = acc0.w;
    pb[(size_t)4 * DSAE] = acc1.x;
    pb[(size_t)5 * DSAE] = acc1.y;
    pb[(size_t)6 * DSAE] = acc1.z;
    pb[(size_t)7 * DSAE] = acc1.w;
}

// ---------------- Kernel 3: combine K-split partials + bias (streaming) ----------------
__global__ __launch_bounds__(256) void combine_kernel(const float* __restrict__ partial,
                                                      const float* __restrict__ b_enc,
                                                      float* __restrict__ pre,
                                                      float* __restrict__ out0) {
    int g  = blockIdx.x * 256 + threadIdx.x;     // float4 index, 0..131071
    int b  = g >> 12;
    int s4 = g & 4095;
    const float4* p = (const float4*)partial;
    float4 acc = p[(size_t)b * 4096 + s4];
    #pragma unroll
    for (int ks = 1; ks < KSPLIT; ++ks) {
        float4 v = p[(size_t)(ks * 32 + b) * 4096 + s4];
        acc.x += v.x; acc.y += v.y; acc.z += v.z; acc.w += v.w;
    }
    float4 be = ((const float4*)b_enc)[s4];
    acc.x += be.x; acc.y += be.y; acc.z += be.z; acc.w += be.w;
    ((float4*)pre)[(size_t)b * 4096 + s4] = acc;
    if (g == 0) *out0 = 0.f;
}

// ---------------- Kernel 4: top-k via 4-pass radix select (exact lax.top_k) ----------------
__global__ __launch_bounds__(1024, 1) void topk_kernel(
    float* __restrict__ z,            // in: pre (32 x DSAE); out: sparse z
    float* __restrict__ sel_val,
    int*   __restrict__ sel_idx)
{
    __shared__ unsigned hist[256];
    __shared__ unsigned gsfx[65];
    __shared__ unsigned sfx[257];
    __shared__ int      sdelta;
    __shared__ unsigned scnt;
    __shared__ int      l_idx[K_];
    __shared__ float    l_val[K_];
    __shared__ int      eq_min;

    const int t = threadIdx.x;
    const int b = blockIdx.x;
    float* zrow = z + (size_t)b * DSAE;

    float v[16]; unsigned u[16];
    #pragma unroll
    for (int i = 0; i < 16; ++i) {
        float f = zrow[t + (i << 10)];
        v[i] = f;
        unsigned xb = __float_as_uint(f);
        u[i] = (xb & 0x80000000u) ? ~xb : (xb | 0x80000000u);
    }

    unsigned prefix = 0, pmask = 0;
    int need = K_;

    for (int p = 0; p < 4; ++p) {
        const int shift = 24 - 8 * p;
        if (t < 256) hist[t] = 0;
        __syncthreads();
        #pragma unroll
        for (int i = 0; i < 16; ++i)
            if ((u[i] & pmask) == prefix)
                atomicAdd(&hist[(u[i] >> shift) & 255u], 1u);
        __syncthreads();
        if (t < 64) {
            unsigned s4 = hist[4*t] + hist[4*t+1] + hist[4*t+2] + hist[4*t+3];
            #pragma unroll
            for (int off = 1; off < 64; off <<= 1) {
                unsigned o = __shfl_down(s4, off, 64);
                if (t + off < 64) s4 += o;
            }
            gsfx[t] = s4;
            if (t == 0) gsfx[64] = 0;
        }
        __syncthreads();
        if (t < 256) {
            int q = t >> 2;
            unsigned acc = gsfx[q + 1];
            for (int d = 4*q + 3; d >= t; --d) acc += hist[d];
            sfx[t] = acc;
            if (t == 0) sfx[256] = 0;
        }
        __syncthreads();
        if (t < 256) {
            if (sfx[t] >= (unsigned)need && sfx[t + 1] < (unsigned)need) sdelta = t;
        }
        __syncthreads();
        const int dlt = sdelta;
        need  -= (int)sfx[dlt + 1];
        prefix |= ((unsigned)dlt) << shift;
        pmask  |= 0xFFu << shift;
        __syncthreads();
    }

    const unsigned ustar = prefix;
    if (t == 0) scnt = 0;
    __syncthreads();

    unsigned eqmask = 0;
    #pragma unroll
    for (int i = 0; i < 16; ++i) {
        int idx = t + (i << 10);
        if (u[i] > ustar) {
            unsigned s = atomicAdd(&scnt, 1u);
            l_idx[s] = idx; l_val[s] = v[i];
        } else if (u[i] == ustar) {
            eqmask |= (1u << i);
        }
    }
    __syncthreads();
    const int needf = need;
    for (int r = 0; r < needf; ++r) {
        if (t == 0) eq_min = 0x7FFFFFFF;
        __syncthreads();
        #pragma unroll
        for (int i = 0; i < 16; ++i)
            if (eqmask & (1u << i)) atomicMin(&eq_min, t + (i << 10));
        __syncthreads();
        #pragma unroll
        for (int i = 0; i < 16; ++i)
            if ((eqmask & (1u << i)) && (t + (i << 10) == eq_min)) {
                eqmask &= ~(1u << i);
                unsigned s = atomicAdd(&scnt, 1u);
                l_idx[s] = eq_min; l_val[s] = v[i];
            }
        __syncthreads();
    }

    #pragma unroll
    for (int i = 0; i < 16; ++i) zrow[t + (i << 10)] = 0.f;
    __syncthreads();
    if (t == 0) {
        for (int a = 1; a < K_; ++a) {
            int ia = l_idx[a]; float va = l_val[a]; int c = a - 1;
            while (c >= 0 && l_idx[c] > ia) {
                l_idx[c+1] = l_idx[c]; l_val[c+1] = l_val[c]; --c;
            }
            l_idx[c+1] = ia; l_val[c+1] = va;
        }
    }
    __syncthreads();
    if (t < K_) {
        float val = l_val[t] > 0.f ? l_val[t] : 0.f;
        zrow[l_idx[t]] = val;
        sel_val[(b << 5) + t] = val;
        sel_idx[(b << 5) + t] = l_idx[t];
    }
}

// ---------------- Kernel 5: sparse decode + fused sq-err, atomic loss ----------------
__global__ __launch_bounds__(256, 4) void decode_kernel(
    const float* __restrict__ W_dec,
    const float* __restrict__ b_dec,
    const float* __restrict__ x,
    const float* __restrict__ sel_val,
    const int*   __restrict__ sel_idx,
    float* __restrict__ xhat,          // d_out + 1
    float* __restrict__ out0)
{
    __shared__ float sv[K_];
    __shared__ int   si[K_];
    __shared__ float wsum[4];

    const int t     = threadIdx.x;
    const int blk   = blockIdx.x;
    const int b     = blk / 12;
    const int chunk = blk - b * 12;

    if (t < K_) { sv[t] = sel_val[(b << 5) + t]; si[t] = sel_idx[(b << 5) + t]; }
    __syncthreads();

    const int e = chunk * 1024 + t * 4;
    float4 acc = *(const float4*)&b_dec[e];
    #pragma unroll 8
    for (int j = 0; j < K_; ++j) {
        const float val = sv[j];
        const float4 wd = *(const float4*)&W_dec[(size_t)si[j] * TD + e];
        acc.x += val * wd.x;
        acc.y += val * wd.y;
        acc.z += val * wd.z;
        acc.w += val * wd.w;
    }

    const size_t xo = (size_t)b * TD + e;
    xhat[xo + 0] = acc.x;
    xhat[xo + 1] = acc.y;
    xhat[xo + 2] = acc.z;
    xhat[xo + 3] = acc.w;

    const float4 xv = *(const float4*)&x[xo];
    float dx = acc.x - xv.x, dy = acc.y - xv.y;
    float dz = acc.z - xv.z, dw = acc.w - xv.w;
    float ss = dx * dx + dy * dy + dz * dz + dw * dw;
    #pragma unroll
    for (int off = 32; off > 0; off >>= 1) ss += __shfl_down(ss, off, 64);
    if ((t & 63) == 0) wsum[t >> 6] = ss;
    __syncthreads();
    if (t == 0)
        atomicAdd(out0, (wsum[0] + wsum[1] + wsum[2] + wsum[3]) * (1.0f / 512.0f));
}

extern "C" void kernel_launch(void* const* d_in, const int* in_sizes, int n_in,
                              void* d_out, int out_size, void* d_ws, size_t ws_size,
                              hipStream_t stream) {
    const float* x      = (const float*)d_in[0];
    const float* conv_w = (const float*)d_in[1];
    const float* b_enc  = (const float*)d_in[2];
    const float* W_dec  = (const float*)d_in[3];
    const float* b_dec  = (const float*)d_in[4];

    float* out  = (float*)d_out;
    float* xhat = out + 1;                        // (32,16,768)
    float* z    = out + 1 + 393216;               // (32,16384) — holds pre then sparse z

    float* partial_enc = (float*)d_ws;                          // 16.8 MB
    float* A_T         = (float*)((char*)d_ws + (20u << 20));   // 288 KB
    float* sel_val     = (float*)((char*)d_ws + (21u << 20));
    int*   sel_idx     = (int*)  ((char*)d_ws + (21u << 20) + 4096);

    prep_kernel    <<<96,   256,  0, stream>>>(x, A_T);
    enc_gemm_kernel<<<2048, 256,  0, stream>>>(conv_w, A_T, partial_enc);
    combine_kernel <<<512,  256,  0, stream>>>(partial_enc, b_enc, z, out);
    topk_kernel    <<<32,   1024, 0, stream>>>(z, sel_val, sel_idx);
    decode_kernel  <<<384,  256,  0, stream>>>(W_dec, b_dec, x, sel_val, sel_idx, xhat, out);
}

// Round 13
// 87.621 us; speedup vs baseline: 10.0573x; 1.5867x over previous
//
#include <hip/hip_runtime.h>
#include <hip/hip_bf16.h>
#include <float.h>

#define DIN   768
#define DSAE  16384
#define K_    32
#define CAND  64      // refinement candidate count
#define KTOT  2304
#define TD    12288   // 16*768
#define KSPLIT 4
#define NCHT  72      // KTOT/32 total chunks
#define NCH   18      // chunks per ksplit

typedef __attribute__((ext_vector_type(8))) short bf16x8;
typedef __attribute__((ext_vector_type(4))) float f32x4;

__device__ __forceinline__ short f2bf(float f) {      // RNE f32->bf16
    unsigned u = __float_as_uint(f);
    u += 0x7FFFu + ((u >> 16) & 1u);
    return (short)(u >> 16);
}

// ---- Kernel 1: prep — A_T[k][b] fp32 + MFMA B-operand fragment buffer bf16 ----
// k = d*3+j; u0 = S - x[b,15,d]; u1 = S; u2 = S - x[b,0,d]
// frag layout: chunk c=k>>5, half h=b>>4, lane=((k&31)>>3)<<4 | (b&15), elem i=k&7
__global__ __launch_bounds__(256) void prep_kernel(const float* __restrict__ x,
                                                   float* __restrict__ A_T,
                                                   short* __restrict__ frag) {
    int g = blockIdx.x * 256 + threadIdx.x;      // 0..24575
    int b = g / DIN;
    int d = g - b * DIN;
    const float* xp = x + (size_t)b * TD + d;
    float S = 0.f;
    float x0 = xp[0];
    float xl = xp[15 * DIN];
    #pragma unroll
    for (int t = 0; t < 16; ++t) S += xp[t * DIN];
    float v0 = S - xl, v1 = S, v2 = S - x0;
    int base = d * 96 + b;
    A_T[base]      = v0;
    A_T[base + 32] = v1;
    A_T[base + 64] = v2;
    const int h = b >> 4, bl = b & 15;
    #pragma unroll
    for (int j = 0; j < 3; ++j) {
        int k = 3 * d + j;
        float val = (j == 0) ? v0 : (j == 1) ? v1 : v2;
        int c = k >> 5, kk = k & 31;
        size_t idx = (((size_t)(c * 2 + h) * 64) + (((kk >> 3) << 4) | bl)) * 8 + (kk & 7);
        frag[idx] = f2bf(val);
    }
}

// ---- Kernel 2: encode GEMM via MFMA 16x16x32 bf16 — no LDS, no barriers ----
// grid 1024 x 256: wave = one 16-row W strip x one k-quarter. Per chunk:
// 2 global float4 (W fp32) -> cvt bf16 -> A-op; 2 frag b128 (L2) -> B-op; 2 MFMA.
__global__ __launch_bounds__(256, 4) void enc_mfma_kernel(
    const float* __restrict__ W,      // conv_w (16384 x 2304)
    const short* __restrict__ frag,   // (72 x 2 x 64 x 8) bf16
    float* __restrict__ partial)      // (4 x 32 x 16384)
{
    const int tid  = threadIdx.x;
    const int bid  = blockIdx.x;
    const int ks   = bid & 3;
    const int l    = tid & 63;
    const int w    = tid >> 6;
    const int strip = (bid >> 2) * 4 + w;        // 0..1023
    const int s0    = strip << 4;
    const int row   = s0 + (l & 15);
    const int klane = (l >> 4) << 3;

    const float* wrow = W + (size_t)row * KTOT;

    f32x4 acc0 = {0.f, 0.f, 0.f, 0.f};
    f32x4 acc1 = {0.f, 0.f, 0.f, 0.f};

    #pragma unroll 2
    for (int ch = 0; ch < NCH; ++ch) {
        const int cg = ks * NCH + ch;
        const int kb = (cg << 5) + klane;
        const float4 wa = *(const float4*)&wrow[kb];
        const float4 wb = *(const float4*)&wrow[kb + 4];
        bf16x8 wf;
        wf[0] = f2bf(wa.x); wf[1] = f2bf(wa.y); wf[2] = f2bf(wa.z); wf[3] = f2bf(wa.w);
        wf[4] = f2bf(wb.x); wf[5] = f2bf(wb.y); wf[6] = f2bf(wb.z); wf[7] = f2bf(wb.w);
        const bf16x8 a0 = *(const bf16x8*)&frag[((size_t)(cg * 2    ) * 64 + l) * 8];
        const bf16x8 a1 = *(const bf16x8*)&frag[((size_t)(cg * 2 + 1) * 64 + l) * 8];
        acc0 = __builtin_amdgcn_mfma_f32_16x16x32_bf16(wf, a0, acc0, 0, 0, 0);
        acc1 = __builtin_amdgcn_mfma_f32_16x16x32_bf16(wf, a1, acc1, 0, 0, 0);
    }

    // C/D: col=lane&15 (b), row=(lane>>4)*4+reg (s)  [m89]
    const int bcol  = l & 15;
    const int sbase = s0 + ((l >> 4) << 2);
    float* p0 = partial + ((size_t)(ks * 32) + bcol) * DSAE + sbase;
    float* p1 = p0 + (size_t)16 * DSAE;
    #pragma unroll
    for (int r = 0; r < 4; ++r) { p0[r] = acc0[r]; p1[r] = acc1[r]; }
}

// ---- Kernel 3: combine 4 K-split partials + bias (streaming) ----
__global__ __launch_bounds__(256) void combine_kernel(const float* __restrict__ partial,
                                                      const float* __restrict__ b_enc,
                                                      float* __restrict__ pre,
                                                      float* __restrict__ out0) {
    int g  = blockIdx.x * 256 + threadIdx.x;     // float4 index, 0..131071
    int b  = g >> 12;
    int s4 = g & 4095;
    const float4* p = (const float4*)partial;
    float4 acc = p[(size_t)b * 4096 + s4];
    #pragma unroll
    for (int ks = 1; ks < KSPLIT; ++ks) {
        float4 v = p[(size_t)(ks * 32 + b) * 4096 + s4];
        acc.x += v.x; acc.y += v.y; acc.z += v.z; acc.w += v.w;
    }
    float4 be = ((const float4*)b_enc)[s4];
    acc.x += be.x; acc.y += be.y; acc.z += be.z; acc.w += be.w;
    ((float4*)pre)[(size_t)b * 4096 + s4] = acc;
    if (g == 0) *out0 = 0.f;
}

// ---- Kernel 4: radix top-64 candidates -> exact fp32 refine -> exact top-32 ----
__global__ __launch_bounds__(1024, 1) void topk_kernel(
    float* __restrict__ z,            // in: approx pre (32 x DSAE); out: sparse z
    const float* __restrict__ A_T,    // (2304 x 32) fp32 exact
    const float* __restrict__ W,      // conv_w
    const float* __restrict__ b_enc,
    float* __restrict__ sel_val,
    int*   __restrict__ sel_idx)
{
    __shared__ unsigned hist[256];
    __shared__ unsigned gsfx[65];
    __shared__ unsigned sfx[257];
    __shared__ int      sdelta;
    __shared__ unsigned scnt;
    __shared__ int      l_idx[CAND];
    __shared__ float    ex_val[CAND];
    __shared__ int      rnk[CAND];
    __shared__ int      eq_min;
    __shared__ float    A_col[KTOT];

    const int t = threadIdx.x;
    const int b = blockIdx.x;
    float* zrow = z + (size_t)b * DSAE;

    unsigned u[16];
    #pragma unroll
    for (int i = 0; i < 16; ++i) {
        unsigned xb = __float_as_uint(zrow[t + (i << 10)]);
        u[i] = (xb & 0x80000000u) ? ~xb : (xb | 0x80000000u);
    }

    // ---- phase A: radix-select the CAND-th largest mapped value ----
    unsigned prefix = 0, pmask = 0;
    int need = CAND;
    for (int p = 0; p < 4; ++p) {
        const int shift = 24 - 8 * p;
        if (t < 256) hist[t] = 0;
        __syncthreads();
        #pragma unroll
        for (int i = 0; i < 16; ++i)
            if ((u[i] & pmask) == prefix)
                atomicAdd(&hist[(u[i] >> shift) & 255u], 1u);
        __syncthreads();
        if (t < 64) {
            unsigned s4 = hist[4*t] + hist[4*t+1] + hist[4*t+2] + hist[4*t+3];
            #pragma unroll
            for (int off = 1; off < 64; off <<= 1) {
                unsigned o = __shfl_down(s4, off, 64);
                if (t + off < 64) s4 += o;
            }
            gsfx[t] = s4;
            if (t == 0) gsfx[64] = 0;
        }
        __syncthreads();
        if (t < 256) {
            int q = t >> 2;
            unsigned acc = gsfx[q + 1];
            for (int d = 4*q + 3; d >= t; --d) acc += hist[d];
            sfx[t] = acc;
            if (t == 0) sfx[256] = 0;
        }
        __syncthreads();
        if (t < 256) {
            if (sfx[t] >= (unsigned)need && sfx[t + 1] < (unsigned)need) sdelta = t;
        }
        __syncthreads();
        const int dlt = sdelta;
        need  -= (int)sfx[dlt + 1];
        prefix |= ((unsigned)dlt) << shift;
        pmask  |= 0xFFu << shift;
        __syncthreads();
    }

    const unsigned ustar = prefix;
    if (t == 0) scnt = 0;
    __syncthreads();
    unsigned eqmask = 0;
    #pragma unroll
    for (int i = 0; i < 16; ++i) {
        int idx = t + (i << 10);
        if (u[i] > ustar) {
            unsigned s = atomicAdd(&scnt, 1u);
            l_idx[s] = idx;
        } else if (u[i] == ustar) {
            eqmask |= (1u << i);
        }
    }
    __syncthreads();
    const int needf = need;
    for (int r = 0; r < needf; ++r) {
        if (t == 0) eq_min = 0x7FFFFFFF;
        __syncthreads();
        #pragma unroll
        for (int i = 0; i < 16; ++i)
            if (eqmask & (1u << i)) atomicMin(&eq_min, t + (i << 10));
        __syncthreads();
        #pragma unroll
        for (int i = 0; i < 16; ++i)
            if ((eqmask & (1u << i)) && (t + (i << 10) == eq_min)) {
                eqmask &= ~(1u << i);
                unsigned s = atomicAdd(&scnt, 1u);
                l_idx[s] = eq_min;
            }
        __syncthreads();
    }

    // ---- stage A_T column b into LDS ----
    for (int q = t; q < KTOT; q += 1024) A_col[q] = A_T[q * 32 + b];
    __syncthreads();

    // ---- phase B: exact fp32 recompute of the 64 candidates ----
    {
        const int j = t >> 4, t16 = t & 15;
        const int cand = l_idx[j];
        const float* wr = W + (size_t)cand * KTOT;
        float s = 0.f;
        for (int q = t16; q < 576; q += 16) {
            const float4 wv = *(const float4*)&wr[q << 2];
            const int k4 = q << 2;
            s += wv.x * A_col[k4] + wv.y * A_col[k4 + 1]
               + wv.z * A_col[k4 + 2] + wv.w * A_col[k4 + 3];
        }
        s += __shfl_xor(s, 1, 64);
        s += __shfl_xor(s, 2, 64);
        s += __shfl_xor(s, 4, 64);
        s += __shfl_xor(s, 8, 64);
        if (t16 == 0) ex_val[j] = s + b_enc[cand];
    }
    __syncthreads();

    // ---- phase C: exact rank (value desc, idx asc), zero z, scatter ----
    if (t < CAND) {
        float v = ex_val[t]; int ix = l_idx[t];
        int r = 0;
        for (int j2 = 0; j2 < CAND; ++j2) {
            float v2 = ex_val[j2]; int ix2 = l_idx[j2];
            r += (v2 > v || (v2 == v && ix2 < ix)) ? 1 : 0;
        }
        rnk[t] = r;
    }
    __syncthreads();
    #pragma unroll
    for (int i = 0; i < 16; ++i) zrow[t + (i << 10)] = 0.f;
    __syncthreads();
    if (t < CAND && rnk[t] < K_) {
        int ix = l_idx[t];
        float v = ex_val[t];
        int pos = 0;
        for (int j2 = 0; j2 < CAND; ++j2)
            pos += (rnk[j2] < K_ && l_idx[j2] < ix) ? 1 : 0;
        float val = v > 0.f ? v : 0.f;
        zrow[ix] = val;
        sel_val[(b << 5) + pos] = val;
        sel_idx[(b << 5) + pos] = ix;
    }
}

// ---- Kernel 5: sparse decode + fused sq-err, atomic loss ----
__global__ __launch_bounds__(256, 4) void decode_kernel(
    const float* __restrict__ W_dec,
    const float* __restrict__ b_dec,
    const float* __restrict__ x,
    const float* __restrict__ sel_val,
    const int*   __restrict__ sel_idx,
    float* __restrict__ xhat,          // d_out + 1
    float* __restrict__ out0)
{
    __shared__ float sv[K_];
    __shared__ int   si[K_];
    __shared__ float wsum[4];

    const int t     = threadIdx.x;
    const int blk   = blockIdx.x;
    const int b     = blk / 12;
    const int chunk = blk - b * 12;

    if (t < K_) { sv[t] = sel_val[(b << 5) + t]; si[t] = sel_idx[(b << 5) + t]; }
    __syncthreads();

    const int e = chunk * 1024 + t * 4;
    float4 acc = *(const float4*)&b_dec[e];
    #pragma unroll 8
    for (int j = 0; j < K_; ++j) {
        const float val = sv[j];
        const float4 wd = *(const float4*)&W_dec[(size_t)si[j] * TD + e];
        acc.x += val * wd.x;
        acc.y += val * wd.y;
        acc.z += val * wd.z;
        acc.w += val * wd.w;
    }

    const size_t xo = (size_t)b * TD + e;
    xhat[xo + 0] = acc.x;
    xhat[xo + 1] = acc.y;
    xhat[xo + 2] = acc.z;
    xhat[xo + 3] = acc.w;

    const float4 xv = *(const float4*)&x[xo];
    float dx = acc.x - xv.x, dy = acc.y - xv.y;
    float dz = acc.z - xv.z, dw = acc.w - xv.w;
    float ss = dx * dx + dy * dy + dz * dz + dw * dw;
    #pragma unroll
    for (int off = 32; off > 0; off >>= 1) ss += __shfl_down(ss, off, 64);
    if ((t & 63) == 0) wsum[t >> 6] = ss;
    __syncthreads();
    if (t == 0)
        atomicAdd(out0, (wsum[0] + wsum[1] + wsum[2] + wsum[3]) * (1.0f / 512.0f));
}

extern "C" void kernel_launch(void* const* d_in, const int* in_sizes, int n_in,
                              void* d_out, int out_size, void* d_ws, size_t ws_size,
                              hipStream_t stream) {
    const float* x      = (const float*)d_in[0];
    const float* conv_w = (const float*)d_in[1];
    const float* b_enc  = (const float*)d_in[2];
    const float* W_dec  = (const float*)d_in[3];
    const float* b_dec  = (const float*)d_in[4];

    float* out  = (float*)d_out;
    float* xhat = out + 1;                        // (32,16,768)
    float* z    = out + 1 + 393216;               // (32,16384)

    float* partial_enc = (float*)d_ws;                           // 8.4 MB
    float* A_T         = (float*)((char*)d_ws + (12u << 20));    // 288 KB
    short* frag        = (short*)((char*)d_ws + (13u << 20));    // 147 KB
    float* sel_val     = (float*)((char*)d_ws + (14u << 20));
    int*   sel_idx     = (int*)  ((char*)d_ws + (14u << 20) + 4096);

    prep_kernel    <<<96,   256,  0, stream>>>(x, A_T, frag);
    enc_mfma_kernel<<<1024, 256,  0, stream>>>(conv_w, frag, partial_enc);
    combine_kernel <<<512,  256,  0, stream>>>(partial_enc, b_enc, z, out);
    topk_kernel    <<<32,   1024, 0, stream>>>(z, A_T, conv_w, b_enc, sel_val, sel_idx);
    decode_kernel  <<<384,  256,  0, stream>>>(W_dec, b_dec, x, sel_val, sel_idx, xhat, out);
}

// Round 14
// 83.074 us; speedup vs baseline: 10.6077x; 1.0547x over previous
//
#include <hip/hip_runtime.h>
#include <hip/hip_bf16.h>
#include <float.h>

#define DIN   768
#define DSAE  16384
#define K_    32
#define CAND  64      // refinement candidate count
#define KTOT  2304
#define TD    12288   // 16*768
#define KSPLIT 2
#define NCH   36      // chunks of 32 per ksplit

typedef __attribute__((ext_vector_type(8))) short bf16x8;
typedef __attribute__((ext_vector_type(4))) float f32x4;

__device__ __forceinline__ short f2bf(float f) {      // RNE f32->bf16
    unsigned u = __float_as_uint(f);
    u += 0x7FFFu + ((u >> 16) & 1u);
    return (short)(u >> 16);
}

__device__ __forceinline__ void frag_store(short* frag, int k, int b, float val) {
    int c = k >> 5, kk = k & 31;
    size_t idx = (((size_t)(c * 2 + (b >> 4)) * 64) + (((kk >> 3) << 4) | (b & 15))) * 8
               + (kk & 7);
    frag[idx] = f2bf(val);
}

// ---- Kernel 1: prep (4-way t-split) — A_T fp32 + bf16 MFMA B-fragments ----
// 4 threads per (b,d); q=tid&3 owns t-quarter 4q..4q+3. S assembled via shfl_xor.
__global__ __launch_bounds__(256) void prep_kernel(const float* __restrict__ x,
                                                   float* __restrict__ A_T,
                                                   short* __restrict__ frag,
                                                   float* __restrict__ out0) {
    int g = blockIdx.x * 256 + threadIdx.x;      // 0..98303
    int pair = g >> 2, q = g & 3;
    int b = pair / DIN;
    int d = pair - b * DIN;
    const float* xp = x + (size_t)b * TD + d;

    float v0 = xp[(4 * q + 0) * DIN];
    float v1 = xp[(4 * q + 1) * DIN];
    float v2 = xp[(4 * q + 2) * DIN];
    float v3 = xp[(4 * q + 3) * DIN];
    float S = v0 + v1 + v2 + v3;
    S += __shfl_xor(S, 1, 64);
    S += __shfl_xor(S, 2, 64);
    float xf = __shfl_xor(v0, 1, 64);            // q1 <- q0's x[b,0,d]
    float xl = __shfl_xor(v3, 1, 64);            // q2 <- q3's x[b,15,d]

    int base = d * 96 + b;                       // (d*3+j)*32 + b
    int k0 = 3 * d;
    if (q == 0) {
        A_T[base + 32] = S;                      // j=1
    } else if (q == 1) {
        float u2 = S - xf;                       // j=2
        A_T[base + 64] = u2;
        frag_store(frag, k0 + 2, b, u2);
    } else if (q == 2) {
        float u0 = S - xl;                       // j=0
        A_T[base] = u0;
        frag_store(frag, k0, b, u0);
    } else {
        frag_store(frag, k0 + 1, b, S);          // j=1
    }
    if (g == 0) *out0 = 0.f;
}

// ---- Kernel 2: encode GEMM via MFMA 16x16x32 bf16 — no LDS, no barriers ----
// grid 512 x 256: wave = one 16-row W strip x one k-half. Per chunk:
// 2 global float4 (W fp32) -> cvt bf16 -> A-op; 2 frag b128 (L2) -> B-op; 2 MFMA.
__global__ __launch_bounds__(256, 4) void enc_mfma_kernel(
    const float* __restrict__ W,      // conv_w (16384 x 2304)
    const short* __restrict__ frag,   // (72 x 2 x 64 x 8) bf16
    float* __restrict__ partial)      // (2 x 32 x 16384)
{
    const int tid  = threadIdx.x;
    const int bid  = blockIdx.x;
    const int ks   = bid & 1;
    const int l    = tid & 63;
    const int w    = tid >> 6;
    const int strip = (bid >> 1) * 4 + w;        // 0..1023
    const int s0    = strip << 4;
    const int row   = s0 + (l & 15);
    const int klane = (l >> 4) << 3;

    const float* wrow = W + (size_t)row * KTOT;

    f32x4 acc0 = {0.f, 0.f, 0.f, 0.f};
    f32x4 acc1 = {0.f, 0.f, 0.f, 0.f};

    #pragma unroll 2
    for (int ch = 0; ch < NCH; ++ch) {
        const int cg = ks * NCH + ch;
        const int kb = (cg << 5) + klane;
        const float4 wa = *(const float4*)&wrow[kb];
        const float4 wb = *(const float4*)&wrow[kb + 4];
        bf16x8 wf;
        wf[0] = f2bf(wa.x); wf[1] = f2bf(wa.y); wf[2] = f2bf(wa.z); wf[3] = f2bf(wa.w);
        wf[4] = f2bf(wb.x); wf[5] = f2bf(wb.y); wf[6] = f2bf(wb.z); wf[7] = f2bf(wb.w);
        const bf16x8 a0 = *(const bf16x8*)&frag[((size_t)(cg * 2    ) * 64 + l) * 8];
        const bf16x8 a1 = *(const bf16x8*)&frag[((size_t)(cg * 2 + 1) * 64 + l) * 8];
        acc0 = __builtin_amdgcn_mfma_f32_16x16x32_bf16(wf, a0, acc0, 0, 0, 0);
        acc1 = __builtin_amdgcn_mfma_f32_16x16x32_bf16(wf, a1, acc1, 0, 0, 0);
    }

    // C/D: col=lane&15 (b), row=(lane>>4)*4+reg (s)  [m89]
    const int bcol  = l & 15;
    const int sbase = s0 + ((l >> 4) << 2);
    float* p0 = partial + ((size_t)(ks * 32) + bcol) * DSAE + sbase;
    float* p1 = p0 + (size_t)16 * DSAE;
    #pragma unroll
    for (int r = 0; r < 4; ++r) { p0[r] = acc0[r]; p1[r] = acc1[r]; }
}

// ---- Kernel 3: fused combine + radix top-64 + exact fp32 refine + scatter ----
__global__ __launch_bounds__(1024, 1) void topk_kernel(
    const float* __restrict__ partial, // (2 x 32 x 16384)
    const float* __restrict__ b_enc,
    float* __restrict__ z,             // out: sparse z (32 x DSAE)
    const float* __restrict__ A_T,     // (2304 x 32) fp32 exact
    const float* __restrict__ W,       // conv_w
    float* __restrict__ sel_val,
    int*   __restrict__ sel_idx)
{
    __shared__ unsigned hist[256];
    __shared__ unsigned gsfx[65];
    __shared__ unsigned sfx[257];
    __shared__ int      sdelta;
    __shared__ unsigned scnt;
    __shared__ int      l_idx[CAND];
    __shared__ float    ex_val[CAND];
    __shared__ int      rnk[CAND];
    __shared__ int      eq_min;
    __shared__ float    A_col[KTOT];

    const int t = threadIdx.x;
    const int b = blockIdx.x;
    float* zrow = z + (size_t)b * DSAE;

    // combine in registers: pre = b_enc + partial0 + partial1
    unsigned u[16];
    #pragma unroll
    for (int i = 0; i < 16; ++i) {
        const int col = t + (i << 10);
        float f = b_enc[col]
                + partial[(size_t)b * DSAE + col]
                + partial[(size_t)(32 + b) * DSAE + col];
        unsigned xb = __float_as_uint(f);
        u[i] = (xb & 0x80000000u) ? ~xb : (xb | 0x80000000u);
    }

    // ---- phase A: radix-select the CAND-th largest mapped value ----
    unsigned prefix = 0, pmask = 0;
    int need = CAND;
    for (int p = 0; p < 4; ++p) {
        const int shift = 24 - 8 * p;
        if (t < 256) hist[t] = 0;
        __syncthreads();
        #pragma unroll
        for (int i = 0; i < 16; ++i)
            if ((u[i] & pmask) == prefix)
                atomicAdd(&hist[(u[i] >> shift) & 255u], 1u);
        __syncthreads();
        if (t < 64) {
            unsigned s4 = hist[4*t] + hist[4*t+1] + hist[4*t+2] + hist[4*t+3];
            #pragma unroll
            for (int off = 1; off < 64; off <<= 1) {
                unsigned o = __shfl_down(s4, off, 64);
                if (t + off < 64) s4 += o;
            }
            gsfx[t] = s4;
            if (t == 0) gsfx[64] = 0;
        }
        __syncthreads();
        if (t < 256) {
            int q = t >> 2;
            unsigned acc = gsfx[q + 1];
            for (int d = 4*q + 3; d >= t; --d) acc += hist[d];
            sfx[t] = acc;
            if (t == 0) sfx[256] = 0;
        }
        __syncthreads();
        if (t < 256) {
            if (sfx[t] >= (unsigned)need && sfx[t + 1] < (unsigned)need) sdelta = t;
        }
        __syncthreads();
        const int dlt = sdelta;
        need  -= (int)sfx[dlt + 1];
        prefix |= ((unsigned)dlt) << shift;
        pmask  |= 0xFFu << shift;
        __syncthreads();
    }

    const unsigned ustar = prefix;
    if (t == 0) scnt = 0;
    __syncthreads();
    unsigned eqmask = 0;
    #pragma unroll
    for (int i = 0; i < 16; ++i) {
        int idx = t + (i << 10);
        if (u[i] > ustar) {
            unsigned s = atomicAdd(&scnt, 1u);
            l_idx[s] = idx;
        } else if (u[i] == ustar) {
            eqmask |= (1u << i);
        }
    }
    __syncthreads();
    const int needf = need;
    for (int r = 0; r < needf; ++r) {
        if (t == 0) eq_min = 0x7FFFFFFF;
        __syncthreads();
        #pragma unroll
        for (int i = 0; i < 16; ++i)
            if (eqmask & (1u << i)) atomicMin(&eq_min, t + (i << 10));
        __syncthreads();
        #pragma unroll
        for (int i = 0; i < 16; ++i)
            if ((eqmask & (1u << i)) && (t + (i << 10) == eq_min)) {
                eqmask &= ~(1u << i);
                unsigned s = atomicAdd(&scnt, 1u);
                l_idx[s] = eq_min;
            }
        __syncthreads();
    }

    // ---- stage A_T column b into LDS ----
    for (int q = t; q < KTOT; q += 1024) A_col[q] = A_T[q * 32 + b];
    __syncthreads();

    // ---- phase B: exact fp32 recompute of the 64 candidates ----
    {
        const int j = t >> 4, t16 = t & 15;
        const int cand = l_idx[j];
        const float* wr = W + (size_t)cand * KTOT;
        float s = 0.f;
        for (int q = t16; q < 576; q += 16) {
            const float4 wv = *(const float4*)&wr[q << 2];
            const int k4 = q << 2;
            s += wv.x * A_col[k4] + wv.y * A_col[k4 + 1]
               + wv.z * A_col[k4 + 2] + wv.w * A_col[k4 + 3];
        }
        s += __shfl_xor(s, 1, 64);
        s += __shfl_xor(s, 2, 64);
        s += __shfl_xor(s, 4, 64);
        s += __shfl_xor(s, 8, 64);
        if (t16 == 0) ex_val[j] = s + b_enc[cand];
    }
    __syncthreads();

    // ---- phase C: exact rank (value desc, idx asc), zero z, scatter ----
    if (t < CAND) {
        float v = ex_val[t]; int ix = l_idx[t];
        int r = 0;
        for (int j2 = 0; j2 < CAND; ++j2) {
            float v2 = ex_val[j2]; int ix2 = l_idx[j2];
            r += (v2 > v || (v2 == v && ix2 < ix)) ? 1 : 0;
        }
        rnk[t] = r;
    }
    __syncthreads();
    #pragma unroll
    for (int i = 0; i < 16; ++i) zrow[t + (i << 10)] = 0.f;
    __syncthreads();
    if (t < CAND && rnk[t] < K_) {
        int ix = l_idx[t];
        float v = ex_val[t];
        int pos = 0;
        for (int j2 = 0; j2 < CAND; ++j2)
            pos += (rnk[j2] < K_ && l_idx[j2] < ix) ? 1 : 0;
        float val = v > 0.f ? v : 0.f;
        zrow[ix] = val;
        sel_val[(b << 5) + pos] = val;
        sel_idx[(b << 5) + pos] = ix;
    }
}

// ---- Kernel 4: sparse decode + fused sq-err, atomic loss ----
__global__ __launch_bounds__(256, 4) void decode_kernel(
    const float* __restrict__ W_dec,
    const float* __restrict__ b_dec,
    const float* __restrict__ x,
    const float* __restrict__ sel_val,
    const int*   __restrict__ sel_idx,
    float* __restrict__ xhat,          // d_out + 1
    float* __restrict__ out0)
{
    __shared__ float sv[K_];
    __shared__ int   si[K_];
    __shared__ float wsum[4];

    const int t     = threadIdx.x;
    const int blk   = blockIdx.x;
    const int b     = blk / 12;
    const int chunk = blk - b * 12;

    if (t < K_) { sv[t] = sel_val[(b << 5) + t]; si[t] = sel_idx[(b << 5) + t]; }
    __syncthreads();

    const int e = chunk * 1024 + t * 4;
    float4 acc = *(const float4*)&b_dec[e];
    #pragma unroll 8
    for (int j = 0; j < K_; ++j) {
        const float val = sv[j];
        const float4 wd = *(const float4*)&W_dec[(size_t)si[j] * TD + e];
        acc.x += val * wd.x;
        acc.y += val * wd.y;
        acc.z += val * wd.z;
        acc.w += val * wd.w;
    }

    const size_t xo = (size_t)b * TD + e;
    xhat[xo + 0] = acc.x;
    xhat[xo + 1] = acc.y;
    xhat[xo + 2] = acc.z;
    xhat[xo + 3] = acc.w;

    const float4 xv = *(const float4*)&x[xo];
    float dx = acc.x - xv.x, dy = acc.y - xv.y;
    float dz = acc.z - xv.z, dw = acc.w - xv.w;
    float ss = dx * dx + dy * dy + dz * dz + dw * dw;
    #pragma unroll
    for (int off = 32; off > 0; off >>= 1) ss += __shfl_down(ss, off, 64);
    if ((t & 63) == 0) wsum[t >> 6] = ss;
    __syncthreads();
    if (t == 0)
        atomicAdd(out0, (wsum[0] + wsum[1] + wsum[2] + wsum[3]) * (1.0f / 512.0f));
}

extern "C" void kernel_launch(void* const* d_in, const int* in_sizes, int n_in,
                              void* d_out, int out_size, void* d_ws, size_t ws_size,
                              hipStream_t stream) {
    const float* x      = (const float*)d_in[0];
    const float* conv_w = (const float*)d_in[1];
    const float* b_enc  = (const float*)d_in[2];
    const float* W_dec  = (const float*)d_in[3];
    const float* b_dec  = (const float*)d_in[4];

    float* out  = (float*)d_out;
    float* xhat = out + 1;                        // (32,16,768)
    float* z    = out + 1 + 393216;               // (32,16384)

    float* partial_enc = (float*)d_ws;                           // 4.2 MB
    float* A_T         = (float*)((char*)d_ws + (6u << 20));     // 288 KB
    short* frag        = (short*)((char*)d_ws + (7u << 20));     // 147 KB
    float* sel_val     = (float*)((char*)d_ws + (8u << 20));
    int*   sel_idx     = (int*)  ((char*)d_ws + (8u << 20) + 4096);

    prep_kernel    <<<384, 256,  0, stream>>>(x, A_T, frag, out);
    enc_mfma_kernel<<<512, 256,  0, stream>>>(conv_w, frag, partial_enc);
    topk_kernel    <<<32,  1024, 0, stream>>>(partial_enc, b_enc, z, A_T, conv_w,
                                              sel_val, sel_idx);
    decode_kernel  <<<384, 256,  0, stream>>>(W_dec, b_dec, x, sel_val, sel_idx, xhat, out);
}